// Round 3
// baseline (32459.882 us; speedup 1.0000x reference)
//
#include <hip/hip_runtime.h>
#include <math.h>

#define T_LEN 2048
#define B_SZ  32
#define D_IN  128
#define U_SZ  512
#define N_SZ  256
#define GS    64
#define NT    1024
#define NW    512   // reduction writer count (= round-0 thread count)

// workspace offsets (in floats)
constexpr size_t OFF_AM  = 0;                                  // Am [256][256]
constexpr size_t OFF_WMM = OFF_AM  + (size_t)N_SZ*N_SZ;        // Wmm [256][512]
constexpr size_t OFF_BW  = OFF_WMM + (size_t)N_SZ*U_SZ;        // bw [512]
constexpr size_t OFF_UX  = OFF_BW  + U_SZ;                     // ux [2048][32]
constexpr size_t OFF_XT  = OFF_UX  + (size_t)T_LEN*B_SZ;       // xT [2048][128][32]
constexpr size_t OFF_S   = OFF_XT  + (size_t)T_LEN*D_IN*B_SZ;  // S [2][768][32]
constexpr size_t OFF_FLG = OFF_S   + (size_t)2*768*B_SZ;       // flags [64][16]

#define FMA4(A, S0, W0) \
  A.x = fmaf(S0, W0.x, A.x); A.y = fmaf(S0, W0.y, A.y); \
  A.z = fmaf(S0, W0.z, A.z); A.w = fmaf(S0, W0.w, A.w);

// pairwise ks-combine across lane^16 (same wave, same bt/jt, ks xor 1)
#define RED2(v) v += __shfl_xor(v, 16)

// ---- fence-free cross-XCD primitives: sc1 (agent-scope) ops bypass the
// non-coherent per-XCD L2 and are served at the device coherence point ----
__device__ inline float2 ld_agent_f2(const float* p) {
  unsigned long long v = __hip_atomic_load((const unsigned long long*)p,
                                           __ATOMIC_RELAXED, __HIP_MEMORY_SCOPE_AGENT);
  union { unsigned long long u; float2 f; } c; c.u = v; return c.f;
}
__device__ inline void st_agent_f1(float* p, float f) {
  union { float f; unsigned u; } c; c.f = f;
  __hip_atomic_store((unsigned*)p, c.u, __ATOMIC_RELAXED, __HIP_MEMORY_SCOPE_AGENT);
}

// Am[k][j] = AT[k][j] + I + me[k]*BT[j]   (folds m@me term of u into m-recurrence)
__global__ void k_am(const float* __restrict__ AT, const float* __restrict__ me,
                     const float* __restrict__ BT, float* __restrict__ ws) {
  int k = blockIdx.x, j = threadIdx.x;
  float v = AT[(size_t)k*N_SZ + j] + (k == j ? 1.0f : 0.0f) + me[k]*BT[j];
  ws[OFF_AM + (size_t)k*N_SZ + j] = v;
}

// bw[j] = sum_q BT[q]*Wm[q][j]
__global__ void k_bw(const float* __restrict__ BT, const float* __restrict__ Wm,
                     float* __restrict__ ws) {
  int j = blockIdx.x*256 + threadIdx.x;
  float acc = 0.f;
  for (int q = 0; q < N_SZ; ++q) acc += BT[q]*Wm[(size_t)q*U_SZ + j];
  ws[OFF_BW + j] = acc;
}

// Wmm = Am @ Wm   [256][512]
__global__ void k_wmm(const float* __restrict__ Wm, float* __restrict__ ws) {
  __shared__ float amr[N_SZ];
  int k = blockIdx.x, tid = threadIdx.x;
  amr[tid] = ws[OFF_AM + (size_t)k*N_SZ + tid];
  __syncthreads();
  float acc0 = 0.f, acc1 = 0.f;
  for (int q = 0; q < N_SZ; ++q) {
    float a = amr[q];
    acc0 += a * Wm[(size_t)q*U_SZ + tid];
    acc1 += a * Wm[(size_t)q*U_SZ + tid + 256];
  }
  ws[OFF_WMM + (size_t)k*U_SZ + tid]       = acc0;
  ws[OFF_WMM + (size_t)k*U_SZ + tid + 256] = acc1;
}

// ux[t][b] = x[b][t][:] . ie
__global__ void k_ux(const float* __restrict__ x, const float* __restrict__ ie,
                     float* __restrict__ ws) {
  __shared__ __align__(16) float iel[D_IN];
  __shared__ float red[B_SZ*9];
  int t = blockIdx.x, tid = threadIdx.x;
  if (tid < D_IN) iel[tid] = ie[tid];
  __syncthreads();
  int b = tid >> 3, p = tid & 7;
  const float4* xr = (const float4*)(x + ((size_t)b*T_LEN + t)*D_IN);
  const float4* wr = (const float4*)iel;
  float s = 0.f;
  for (int q = 0; q < 4; ++q) {
    int fi = p + q*8;
    float4 v = xr[fi];
    float4 w = wr[fi];
    s += v.x*w.x + v.y*w.y + v.z*w.z + v.w*w.w;
  }
  red[b*9 + p] = s;
  __syncthreads();
  if (tid < B_SZ) {
    float acc = 0.f;
    for (int p2 = 0; p2 < 8; ++p2) acc += red[tid*9 + p2];
    ws[OFF_UX + (size_t)t*B_SZ + tid] = acc;
  }
}

// xT[t][d][b] = x[b][t][d]
__global__ void k_xt(const float* __restrict__ x, float* __restrict__ ws) {
  __shared__ float tile[B_SZ*33];
  int bid = blockIdx.x;
  int t = bid >> 2, d0 = (bid & 3)*32;
  int tid = threadIdx.x;
  int lo = tid & 31, hi = tid >> 5;
  for (int p = 0; p < 4; ++p) {
    int b = hi + p*8;
    tile[b*33 + lo] = x[((size_t)b*T_LEN + t)*D_IN + d0 + lo];
  }
  __syncthreads();
  float* dst = ws + OFF_XT + ((size_t)t*D_IN + d0)*B_SZ;
  for (int p = 0; p < 4; ++p) {
    int d = hi + p*8;
    dst[(size_t)d*B_SZ + lo] = tile[lo*33 + d];
  }
}

// init: S[0] = [h0 | m0] in [k][b]; zero the barrier flags
__global__ void k_init(const float* __restrict__ h0, const float* __restrict__ mm0,
                       float* __restrict__ ws) {
  int bid = blockIdx.x, tid = threadIdx.x;
  if (bid < 24) {
    for (int i = 0; i < 4; ++i) {
      int e = bid*1024 + i*256 + tid;
      int k = e >> 5, b = e & 31;
      float v = (k < U_SZ) ? h0[(size_t)b*U_SZ + k] : mm0[(size_t)b*N_SZ + (k - U_SZ)];
      ws[OFF_S + e] = v;
    }
  } else {
    for (int idx = tid; idx < GS*16; idx += 256) ws[OFF_FLG + idx] = 0.0f;  // 0u bits
  }
}

// persistent scan: GS=64 blocks x NT=1024 threads (16 waves = 4 waves/SIMD at
// 1 block/CU — doubled TLP vs the 512-thread version to hide the ~900cy
// agent-load latency inside seg1/seg2). k is split 64-way (ks in [0,64));
// adjacent ks pairs combine partials in-register via shfl_xor(16) so the
// LDS reduction layout, epilogue, stores, flags and barrier structure are
// IDENTICAL to the proven 512-thread round-0 kernel.
__global__ __launch_bounds__(NT, 4) void k_scan(
    const float* __restrict__ Wh, const float* __restrict__ Wi,
    const float* __restrict__ he, const float* __restrict__ btv,
    float* __restrict__ ws, float* __restrict__ out)
{
  const int g = blockIdx.x, tid = threadIdx.x;
  const int JH = g*8, JM = g*4;
  const int bt = tid & 7, jt = (tid >> 3) & 1, ks = tid >> 4;   // ks in [0,64)
  const int b0 = bt*4;

  float* uxw = ws + OFF_UX;
  float* xT  = ws + OFF_XT;
  float* Sb  = ws + OFF_S;
  unsigned* flags = (unsigned*)(ws + OFF_FLG);

  __shared__ __align__(16) float Wl[896*8];   // [k][jj]: k<512 Wh, <768 Wmm, <896 Wi
  __shared__ __align__(16) float Aml[N_SZ*4]; // [k][jj] m-columns of Am
  __shared__ float Hl[U_SZ];                  // hidden_encoders
  __shared__ float redh[NW*17];
  __shared__ float redm[256*17];
  __shared__ float reds[256*9];
  __shared__ float bwl[8], btl[4];

  for (int idx = tid; idx < 896*8; idx += NT) {
    int k = idx >> 3, jj = idx & 7;
    float v;
    if (k < 512)      v = Wh[(size_t)k*U_SZ + JH + jj];
    else if (k < 768) v = ws[OFF_WMM + (size_t)(k-512)*U_SZ + JH + jj];
    else              v = Wi[(size_t)(k-768)*U_SZ + JH + jj];
    Wl[idx] = v;
  }
  for (int idx = tid; idx < N_SZ*4; idx += NT) {
    int k = idx >> 2, jj = idx & 3;
    Aml[idx] = ws[OFF_AM + (size_t)k*N_SZ + JM + jj];
  }
  for (int idx = tid; idx < U_SZ; idx += NT) Hl[idx] = he[idx];
  if (tid < 8) bwl[tid] = ws[OFF_BW + JH + tid];
  if (tid < 4) btl[tid] = btv[JM + tid];
  __syncthreads();

  const float4* Wl4  = (const float4*)Wl;
  const float4* Aml4 = (const float4*)Aml;

  float4 a0={0,0,0,0}, a1={0,0,0,0}, a2={0,0,0,0}, a3={0,0,0,0};
  // seg3 for t=0 (x_0 @ Wi), local data only
  {
    const float* xrow = xT;
    #pragma unroll
    for (int i = 12; i < 14; ++i) {
      int kk = i*64 + ks;
      float4 sv = *(const float4*)(xrow + (size_t)(kk - 768)*B_SZ + b0);
      float4 wv = Wl4[kk*2 + jt];
      FMA4(a0, sv.x, wv) FMA4(a1, sv.y, wv) FMA4(a2, sv.z, wv) FMA4(a3, sv.w, wv)
    }
  }

  for (int t = 0; t < T_LEN; ++t) {
    const float* S  = Sb + (size_t)(t & 1)*(768*B_SZ);
    float*       Sn = Sb + (size_t)((t+1) & 1)*(768*B_SZ);

    float uxv = uxw[(size_t)t*B_SZ + (tid & 31)];

    float4 q0={0,0,0,0}, q1={0,0,0,0}, q2={0,0,0,0}, q3={0,0,0,0};
    float4 sa={0,0,0,0};

    // seg1: k in [0,512): h x Wh (+ local s-partial h.he)
    #pragma unroll
    for (int i = 0; i < 8; ++i) {
      int kk = i*64 + ks;
      const float* sp0 = S + (size_t)kk*B_SZ + b0;
      float2 s01 = ld_agent_f2(sp0);
      float2 s23 = ld_agent_f2(sp0 + 2);
      float4 wv = Wl4[kk*2 + jt];
      float hv = Hl[kk];
      FMA4(a0, s01.x, wv) FMA4(a1, s01.y, wv) FMA4(a2, s23.x, wv) FMA4(a3, s23.y, wv)
      sa.x = fmaf(s01.x, hv, sa.x); sa.y = fmaf(s01.y, hv, sa.y);
      sa.z = fmaf(s23.x, hv, sa.z); sa.w = fmaf(s23.y, hv, sa.w);
    }
    // seg2: k in [512,768): m x Wmm  +  m x Am
    #pragma unroll
    for (int i = 8; i < 12; ++i) {
      int kk = i*64 + ks;
      const float* sp0 = S + (size_t)kk*B_SZ + b0;
      float2 s01 = ld_agent_f2(sp0);
      float2 s23 = ld_agent_f2(sp0 + 2);
      float4 wv = Wl4[kk*2 + jt];
      FMA4(a0, s01.x, wv) FMA4(a1, s01.y, wv) FMA4(a2, s23.x, wv) FMA4(a3, s23.y, wv)
      float4 av = Aml4[kk - 512];
      FMA4(q0, s01.x, av) FMA4(q1, s01.y, av) FMA4(q2, s23.x, av) FMA4(q3, s23.y, av)
    }

    // in-register ks-pair combine (partner lane^16: same bt/jt, ks^1)
    RED2(a0.x); RED2(a0.y); RED2(a0.z); RED2(a0.w);
    RED2(a1.x); RED2(a1.y); RED2(a1.z); RED2(a1.w);
    RED2(a2.x); RED2(a2.y); RED2(a2.z); RED2(a2.w);
    RED2(a3.x); RED2(a3.y); RED2(a3.z); RED2(a3.w);
    RED2(sa.x); RED2(sa.y); RED2(sa.z); RED2(sa.w);
    if (jt == 0) {  // partner lane is also jt==0 — uniform within the pair
      RED2(q0.x); RED2(q0.y); RED2(q0.z); RED2(q0.w);
      RED2(q1.x); RED2(q1.y); RED2(q1.z); RED2(q1.w);
      RED2(q2.x); RED2(q2.y); RED2(q2.z); RED2(q2.w);
      RED2(q3.x); RED2(q3.y); RED2(q3.z); RED2(q3.w);
    }

    // partials to LDS — even-ks writers only; layout identical to round-0
    if (!(ks & 1)) {
      const int wt = bt + 8*jt + 16*(ks >> 1);
      float* rp = redh + wt*17;
      rp[0]=a0.x;  rp[1]=a0.y;  rp[2]=a0.z;  rp[3]=a0.w;
      rp[4]=a1.x;  rp[5]=a1.y;  rp[6]=a1.z;  rp[7]=a1.w;
      rp[8]=a2.x;  rp[9]=a2.y;  rp[10]=a2.z; rp[11]=a2.w;
      rp[12]=a3.x; rp[13]=a3.y; rp[14]=a3.z; rp[15]=a3.w;
      if (jt == 0) {
        const int idx = bt + 8*(ks >> 1);
        float* rm = redm + idx*17;
        rm[0]=q0.x;  rm[1]=q0.y;  rm[2]=q0.z;  rm[3]=q0.w;
        rm[4]=q1.x;  rm[5]=q1.y;  rm[6]=q1.z;  rm[7]=q1.w;
        rm[8]=q2.x;  rm[9]=q2.y;  rm[10]=q2.z; rm[11]=q2.w;
        rm[12]=q3.x; rm[13]=q3.y; rm[14]=q3.z; rm[15]=q3.w;
        float* rs = reds + idx*9;
        rs[0]=sa.x; rs[1]=sa.y; rs[2]=sa.z; rs[3]=sa.w;
      }
    }
    __syncthreads();   // (A)

    // epilogue: tid<256 -> h-cols (be,je); tid in [256,384) -> m-cols (be,jm)
    float val = 0.f;
    if (tid < 384) {
      const int be2 = tid & 31, btb = be2 >> 2, xx = be2 & 3;
      float ssb = uxv;
      #pragma unroll
      for (int k2 = 0; k2 < 32; ++k2) ssb += reds[(btb + 8*k2)*9 + xx];
      if (tid < 256) {
        const int je = tid >> 5, jt2 = je >> 2, yy = je & 3;
        float sum = 0.f;
        #pragma unroll
        for (int k2 = 0; k2 < 32; ++k2)
          sum += redh[(btb + 8*jt2 + 16*k2)*17 + xx*4 + yy];
        val = tanhf(sum + ssb*bwl[je]);
        st_agent_f1(Sn + (size_t)(JH + je)*B_SZ + be2, val);
      } else {
        const int jm = (tid - 256) >> 5;
        float sum = 0.f;
        #pragma unroll
        for (int k2 = 0; k2 < 32; ++k2)
          sum += redm[(btb + 8*k2)*17 + xx*4 + jm];
        sum += ssb*btl[jm];
        st_agent_f1(Sn + (size_t)(512 + JM + jm)*B_SZ + be2, sum);
      }
    }
    __syncthreads();   // (B) — implicit vmcnt(0): all Sn sc1 stores are at IC

    // arrival flag ASAP, then off-critical-path work in the barrier shadow
    if (t + 1 < T_LEN && tid == 0)
      __hip_atomic_store(flags + (size_t)g*16, (unsigned)(t + 1),
                         __ATOMIC_RELAXED, __HIP_MEMORY_SCOPE_AGENT);
    if (tid < 256)
      out[((size_t)(tid & 31)*T_LEN + t)*U_SZ + JH + (tid >> 5)] = val;

    a0.x=a0.y=a0.z=a0.w=0.f; a1=a0; a2=a0; a3=a0;
    if (t + 1 < T_LEN) {
      const float* xrow = xT + (size_t)(t+1)*D_IN*B_SZ;
      #pragma unroll
      for (int i = 12; i < 14; ++i) {
        int kk = i*64 + ks;
        float4 sv = *(const float4*)(xrow + (size_t)(kk - 768)*B_SZ + b0);
        float4 wv = Wl4[kk*2 + jt];
        FMA4(a0, sv.x, wv) FMA4(a1, sv.y, wv) FMA4(a2, sv.z, wv) FMA4(a3, sv.w, wv)
      }
      if (tid < 64) {
        const unsigned* fp = flags + (size_t)tid*16;
        while (__hip_atomic_load(fp, __ATOMIC_RELAXED, __HIP_MEMORY_SCOPE_AGENT)
               < (unsigned)(t + 1)) { }
      }
    }
    __syncthreads();   // (C)
  }
}

extern "C" void kernel_launch(void* const* d_in, const int* in_sizes, int n_in,
                              void* d_out, int out_size, void* d_ws, size_t ws_size,
                              hipStream_t stream) {
  const float* x   = (const float*)d_in[0];
  const float* h0  = (const float*)d_in[1];
  const float* m0  = (const float*)d_in[2];
  const float* ie  = (const float*)d_in[3];
  const float* he  = (const float*)d_in[4];
  const float* me  = (const float*)d_in[5];
  const float* Wi  = (const float*)d_in[6];
  const float* Wh  = (const float*)d_in[7];
  const float* Wm  = (const float*)d_in[8];
  const float* AT  = (const float*)d_in[9];
  const float* BT  = (const float*)d_in[10];
  float* ws  = (float*)d_ws;
  float* out = (float*)d_out;

  k_am  <<<N_SZ, 256, 0, stream>>>(AT, me, BT, ws);
  k_bw  <<<2, 256, 0, stream>>>(BT, Wm, ws);
  k_wmm <<<N_SZ, 256, 0, stream>>>(Wm, ws);
  k_ux  <<<T_LEN, 256, 0, stream>>>(x, ie, ws);
  k_xt  <<<T_LEN*4, 256, 0, stream>>>(x, ws);
  k_init<<<25, 256, 0, stream>>>(h0, m0, ws);
  k_scan<<<GS, NT, 0, stream>>>(Wh, Wi, he, BT, ws, out);
}

// Round 4
// 10610.181 us; speedup vs baseline: 3.0593x; 3.0593x over previous
//
#include <hip/hip_runtime.h>
#include <math.h>

#define T_LEN 2048
#define B_SZ  32
#define D_IN  128
#define U_SZ  512
#define N_SZ  256
#define GS    128
#define NT    512

// workspace offsets (in floats)
constexpr size_t OFF_AM  = 0;                                  // Am [256][256]
constexpr size_t OFF_WMM = OFF_AM  + (size_t)N_SZ*N_SZ;        // Wmm [256][512]
constexpr size_t OFF_BW  = OFF_WMM + (size_t)N_SZ*U_SZ;        // bw [512]
constexpr size_t OFF_UX  = OFF_BW  + U_SZ;                     // ux [2048][32]
constexpr size_t OFF_XT  = OFF_UX  + (size_t)T_LEN*B_SZ;       // xT [2048][128][32]
constexpr size_t OFF_S   = OFF_XT  + (size_t)T_LEN*D_IN*B_SZ;  // S [2][768][32]
constexpr size_t OFF_FLG = OFF_S   + (size_t)2*768*B_SZ;       // flags [128][16]

#define FMA4(A, S0, W0) \
  A.x = fmaf(S0, W0.x, A.x); A.y = fmaf(S0, W0.y, A.y); \
  A.z = fmaf(S0, W0.z, A.z); A.w = fmaf(S0, W0.w, A.w);

// one butterfly round over all 28 partial values (same bt, ks^mask/8)
#define REDR(m) \
  a0.x += __shfl_xor(a0.x,(m)); a0.y += __shfl_xor(a0.y,(m)); \
  a0.z += __shfl_xor(a0.z,(m)); a0.w += __shfl_xor(a0.w,(m)); \
  a1.x += __shfl_xor(a1.x,(m)); a1.y += __shfl_xor(a1.y,(m)); \
  a1.z += __shfl_xor(a1.z,(m)); a1.w += __shfl_xor(a1.w,(m)); \
  a2.x += __shfl_xor(a2.x,(m)); a2.y += __shfl_xor(a2.y,(m)); \
  a2.z += __shfl_xor(a2.z,(m)); a2.w += __shfl_xor(a2.w,(m)); \
  a3.x += __shfl_xor(a3.x,(m)); a3.y += __shfl_xor(a3.y,(m)); \
  a3.z += __shfl_xor(a3.z,(m)); a3.w += __shfl_xor(a3.w,(m)); \
  q0.x += __shfl_xor(q0.x,(m)); q0.y += __shfl_xor(q0.y,(m)); \
  q0.z += __shfl_xor(q0.z,(m)); q0.w += __shfl_xor(q0.w,(m)); \
  q1.x += __shfl_xor(q1.x,(m)); q1.y += __shfl_xor(q1.y,(m)); \
  q1.z += __shfl_xor(q1.z,(m)); q1.w += __shfl_xor(q1.w,(m)); \
  sa.x += __shfl_xor(sa.x,(m)); sa.y += __shfl_xor(sa.y,(m)); \
  sa.z += __shfl_xor(sa.z,(m)); sa.w += __shfl_xor(sa.w,(m));

// ---- fence-free cross-XCD primitives: sc1 (agent-scope) ops bypass the
// non-coherent per-XCD L2 and are served at the device coherence point ----
__device__ inline float2 ld_agent_f2(const float* p) {
  unsigned long long v = __hip_atomic_load((const unsigned long long*)p,
                                           __ATOMIC_RELAXED, __HIP_MEMORY_SCOPE_AGENT);
  union { unsigned long long u; float2 f; } c; c.u = v; return c.f;
}
__device__ inline void st_agent_f1(float* p, float f) {
  union { float f; unsigned u; } c; c.f = f;
  __hip_atomic_store((unsigned*)p, c.u, __ATOMIC_RELAXED, __HIP_MEMORY_SCOPE_AGENT);
}

// Am[k][j] = AT[k][j] + I + me[k]*BT[j]   (folds m@me term of u into m-recurrence)
__global__ void k_am(const float* __restrict__ AT, const float* __restrict__ me,
                     const float* __restrict__ BT, float* __restrict__ ws) {
  int k = blockIdx.x, j = threadIdx.x;
  float v = AT[(size_t)k*N_SZ + j] + (k == j ? 1.0f : 0.0f) + me[k]*BT[j];
  ws[OFF_AM + (size_t)k*N_SZ + j] = v;
}

// bw[j] = sum_q BT[q]*Wm[q][j]
__global__ void k_bw(const float* __restrict__ BT, const float* __restrict__ Wm,
                     float* __restrict__ ws) {
  int j = blockIdx.x*256 + threadIdx.x;
  float acc = 0.f;
  for (int q = 0; q < N_SZ; ++q) acc += BT[q]*Wm[(size_t)q*U_SZ + j];
  ws[OFF_BW + j] = acc;
}

// Wmm = Am @ Wm   [256][512]
__global__ void k_wmm(const float* __restrict__ Wm, float* __restrict__ ws) {
  __shared__ float amr[N_SZ];
  int k = blockIdx.x, tid = threadIdx.x;
  amr[tid] = ws[OFF_AM + (size_t)k*N_SZ + tid];
  __syncthreads();
  float acc0 = 0.f, acc1 = 0.f;
  for (int q = 0; q < N_SZ; ++q) {
    float a = amr[q];
    acc0 += a * Wm[(size_t)q*U_SZ + tid];
    acc1 += a * Wm[(size_t)q*U_SZ + tid + 256];
  }
  ws[OFF_WMM + (size_t)k*U_SZ + tid]       = acc0;
  ws[OFF_WMM + (size_t)k*U_SZ + tid + 256] = acc1;
}

// ux[t][b] = x[b][t][:] . ie
__global__ void k_ux(const float* __restrict__ x, const float* __restrict__ ie,
                     float* __restrict__ ws) {
  __shared__ __align__(16) float iel[D_IN];
  __shared__ float red[B_SZ*9];
  int t = blockIdx.x, tid = threadIdx.x;
  if (tid < D_IN) iel[tid] = ie[tid];
  __syncthreads();
  int b = tid >> 3, p = tid & 7;
  const float4* xr = (const float4*)(x + ((size_t)b*T_LEN + t)*D_IN);
  const float4* wr = (const float4*)iel;
  float s = 0.f;
  for (int q = 0; q < 4; ++q) {
    int fi = p + q*8;
    float4 v = xr[fi];
    float4 w = wr[fi];
    s += v.x*w.x + v.y*w.y + v.z*w.z + v.w*w.w;
  }
  red[b*9 + p] = s;
  __syncthreads();
  if (tid < B_SZ) {
    float acc = 0.f;
    for (int p2 = 0; p2 < 8; ++p2) acc += red[tid*9 + p2];
    ws[OFF_UX + (size_t)t*B_SZ + tid] = acc;
  }
}

// xT[t][d][b] = x[b][t][d]
__global__ void k_xt(const float* __restrict__ x, float* __restrict__ ws) {
  __shared__ float tile[B_SZ*33];
  int bid = blockIdx.x;
  int t = bid >> 2, d0 = (bid & 3)*32;
  int tid = threadIdx.x;
  int lo = tid & 31, hi = tid >> 5;
  for (int p = 0; p < 4; ++p) {
    int b = hi + p*8;
    tile[b*33 + lo] = x[((size_t)b*T_LEN + t)*D_IN + d0 + lo];
  }
  __syncthreads();
  float* dst = ws + OFF_XT + ((size_t)t*D_IN + d0)*B_SZ;
  for (int p = 0; p < 4; ++p) {
    int d = hi + p*8;
    dst[(size_t)d*B_SZ + lo] = tile[lo*33 + d];
  }
}

// init: S[0] = [h0 | m0] in [k][b]; zero the barrier flags
__global__ void k_init(const float* __restrict__ h0, const float* __restrict__ mm0,
                       float* __restrict__ ws) {
  int bid = blockIdx.x, tid = threadIdx.x;
  if (bid < 24) {
    for (int i = 0; i < 4; ++i) {
      int e = bid*1024 + i*256 + tid;
      int k = e >> 5, b = e & 31;
      float v = (k < U_SZ) ? h0[(size_t)b*U_SZ + k] : mm0[(size_t)b*N_SZ + (k - U_SZ)];
      ws[OFF_S + e] = v;
    }
  } else {
    for (int idx = tid; idx < GS*16; idx += 256) ws[OFF_FLG + idx] = 0.0f;  // 0u bits
  }
}

// persistent scan: GS=128 blocks x NT=512 threads (128 CUs, 8 waves each).
// Block g owns h-cols [g*4, g*4+4) and m-cols [g*2, g*2+2).
// vs the 64-block version: no jt duplication (each state element loaded ONCE,
// 24 f2/thread), per-thread FMA halved, accumulators j-major so partials
// reduce in-wave (3 shfl_xor rounds over ks) to 64 LDS writers + 8-deep
// epilogue. Exchange protocol (stores -> sync(B) -> flag -> poll -> sync(C))
// is identical to the proven round-0 kernel, with 128 flags.
__global__ __launch_bounds__(NT, 2) void k_scan(
    const float* __restrict__ Wh, const float* __restrict__ Wi,
    const float* __restrict__ he, const float* __restrict__ btv,
    float* __restrict__ ws, float* __restrict__ out)
{
  const int g = blockIdx.x, tid = threadIdx.x;
  const int JH = g*4, JM = g*2;
  const int bt = tid & 7, ks = tid >> 3;   // ks in [0,64)
  const int b0 = bt*4;

  float* uxw = ws + OFF_UX;
  float* xT  = ws + OFF_XT;
  float* Sb  = ws + OFF_S;
  unsigned* flags = (unsigned*)(ws + OFF_FLG);

  __shared__ __align__(16) float Wl[896*4];   // [k][j]: k<512 Wh, <768 Wmm, <896 Wi
  __shared__ __align__(16) float Aml[N_SZ*2]; // [k][jm] m-columns of Am
  __shared__ float Hl[U_SZ];                  // hidden_encoders
  __shared__ __align__(16) float redh[64*20]; // [writer][j*4+b]
  __shared__ __align__(16) float redm[64*12]; // [writer][jm*4+b]
  __shared__ __align__(16) float reds[64*8];  // [writer][b]
  __shared__ float bwl[4], btl[2];

  for (int idx = tid; idx < 896*4; idx += NT) {
    int k = idx >> 2, jj = idx & 3;
    float v;
    if (k < 512)      v = Wh[(size_t)k*U_SZ + JH + jj];
    else if (k < 768) v = ws[OFF_WMM + (size_t)(k-512)*U_SZ + JH + jj];
    else              v = Wi[(size_t)(k-768)*U_SZ + JH + jj];
    Wl[idx] = v;
  }
  for (int idx = tid; idx < N_SZ*2; idx += NT) {
    int k = idx >> 1, jj = idx & 1;
    Aml[idx] = ws[OFF_AM + (size_t)k*N_SZ + JM + jj];
  }
  for (int idx = tid; idx < U_SZ; idx += NT) Hl[idx] = he[idx];
  if (tid < 4) bwl[tid] = ws[OFF_BW + JH + tid];
  if (tid < 2) btl[tid] = btv[JM + tid];
  __syncthreads();

  const float4* Wl4  = (const float4*)Wl;
  const float2* Aml2 = (const float2*)Aml;

  // accumulators: a{0..3} = h-col JH+{0..3} over this thread's 4 batches;
  // q{0,1} = m-col JM+{0,1}; sa = h.he partial.
  float4 a0={0,0,0,0}, a1={0,0,0,0}, a2={0,0,0,0}, a3={0,0,0,0};
  // seg3 for t=0 (x_0 @ Wi), local data only
  {
    const float* xrow = xT;
    #pragma unroll
    for (int i = 12; i < 14; ++i) {
      int kk = i*64 + ks;
      float4 sv = *(const float4*)(xrow + (size_t)(kk - 768)*B_SZ + b0);
      float4 wv = Wl4[kk];
      FMA4(a0, wv.x, sv) FMA4(a1, wv.y, sv) FMA4(a2, wv.z, sv) FMA4(a3, wv.w, sv)
    }
  }

  for (int t = 0; t < T_LEN; ++t) {
    const float* S  = Sb + (size_t)(t & 1)*(768*B_SZ);
    float*       Sn = Sb + (size_t)((t+1) & 1)*(768*B_SZ);

    float uxv = uxw[(size_t)t*B_SZ + (tid & 31)];

    float4 q0={0,0,0,0}, q1={0,0,0,0};
    float4 sa={0,0,0,0};

    // seg1: k in [0,512): h x Wh (+ local s-partial h.he)
    #pragma unroll
    for (int i = 0; i < 8; ++i) {
      int kk = i*64 + ks;
      const float* sp0 = S + (size_t)kk*B_SZ + b0;
      float2 s01 = ld_agent_f2(sp0);
      float2 s23 = ld_agent_f2(sp0 + 2);
      float4 sv = {s01.x, s01.y, s23.x, s23.y};
      float4 wv = Wl4[kk];
      float hv = Hl[kk];
      FMA4(a0, wv.x, sv) FMA4(a1, wv.y, sv) FMA4(a2, wv.z, sv) FMA4(a3, wv.w, sv)
      FMA4(sa, hv, sv)
    }
    // seg2: k in [512,768): m x Wmm  +  m x Am
    #pragma unroll
    for (int i = 8; i < 12; ++i) {
      int kk = i*64 + ks;
      const float* sp0 = S + (size_t)kk*B_SZ + b0;
      float2 s01 = ld_agent_f2(sp0);
      float2 s23 = ld_agent_f2(sp0 + 2);
      float4 sv = {s01.x, s01.y, s23.x, s23.y};
      float4 wv = Wl4[kk];
      FMA4(a0, wv.x, sv) FMA4(a1, wv.y, sv) FMA4(a2, wv.z, sv) FMA4(a3, wv.w, sv)
      float2 av = Aml2[kk - 512];
      FMA4(q0, av.x, sv) FMA4(q1, av.y, sv)
    }

    // in-wave ks-reduction: 3 butterfly rounds (ks^1, ks^2, ks^4 in-wave)
    REDR(8) REDR(16) REDR(32)

    // LDS partials: one writer per (bt, wave) = 64 writers
    if ((tid & 56) == 0) {
      const int wi = bt + 8*(tid >> 6);
      float4* rp = (float4*)(redh + wi*20);
      rp[0] = a0; rp[1] = a1; rp[2] = a2; rp[3] = a3;
      float4* rm = (float4*)(redm + wi*12);
      rm[0] = q0; rm[1] = q1;
      *(float4*)(reds + wi*8) = sa;
    }
    __syncthreads();   // (A)

    // epilogue: tid<128 -> h-cols (be,je); tid in [128,192) -> m-cols (be,jm)
    float val = 0.f;
    if (tid < 192) {
      const int be2 = tid & 31, btb = be2 >> 2, xx = be2 & 3;
      float ssb = uxv;
      #pragma unroll
      for (int wv = 0; wv < 8; ++wv) ssb += reds[(btb + 8*wv)*8 + xx];
      if (tid < 128) {
        const int je = tid >> 5;
        float sum = 0.f;
        #pragma unroll
        for (int wv = 0; wv < 8; ++wv)
          sum += redh[(btb + 8*wv)*20 + je*4 + xx];
        val = tanhf(sum + ssb*bwl[je]);
        st_agent_f1(Sn + (size_t)(JH + je)*B_SZ + be2, val);
      } else {
        const int jm = (tid - 128) >> 5;
        float sum = 0.f;
        #pragma unroll
        for (int wv = 0; wv < 8; ++wv)
          sum += redm[(btb + 8*wv)*12 + jm*4 + xx];
        sum += ssb*btl[jm];
        st_agent_f1(Sn + (size_t)(512 + JM + jm)*B_SZ + be2, sum);
      }
    }
    __syncthreads();   // (B) — implicit vmcnt(0): all Sn sc1 stores are at IC

    // arrival flag ASAP, then off-critical-path work in the barrier shadow
    if (t + 1 < T_LEN && tid == 0)
      __hip_atomic_store(flags + (size_t)g*16, (unsigned)(t + 1),
                         __ATOMIC_RELAXED, __HIP_MEMORY_SCOPE_AGENT);
    if (tid < 128)
      out[((size_t)(tid & 31)*T_LEN + t)*U_SZ + JH + (tid >> 5)] = val;

    a0.x=a0.y=a0.z=a0.w=0.f; a1=a0; a2=a0; a3=a0;
    if (t + 1 < T_LEN) {
      const float* xrow = xT + (size_t)(t+1)*D_IN*B_SZ;
      #pragma unroll
      for (int i = 12; i < 14; ++i) {
        int kk = i*64 + ks;
        float4 sv = *(const float4*)(xrow + (size_t)(kk - 768)*B_SZ + b0);
        float4 wv = Wl4[kk];
        FMA4(a0, wv.x, sv) FMA4(a1, wv.y, sv) FMA4(a2, wv.z, sv) FMA4(a3, wv.w, sv)
      }
      if (tid < GS) {
        const unsigned* fp = flags + (size_t)tid*16;
        while (__hip_atomic_load(fp, __ATOMIC_RELAXED, __HIP_MEMORY_SCOPE_AGENT)
               < (unsigned)(t + 1)) { }
      }
    }
    __syncthreads();   // (C)
  }
}

extern "C" void kernel_launch(void* const* d_in, const int* in_sizes, int n_in,
                              void* d_out, int out_size, void* d_ws, size_t ws_size,
                              hipStream_t stream) {
  const float* x   = (const float*)d_in[0];
  const float* h0  = (const float*)d_in[1];
  const float* m0  = (const float*)d_in[2];
  const float* ie  = (const float*)d_in[3];
  const float* he  = (const float*)d_in[4];
  const float* me  = (const float*)d_in[5];
  const float* Wi  = (const float*)d_in[6];
  const float* Wh  = (const float*)d_in[7];
  const float* Wm  = (const float*)d_in[8];
  const float* AT  = (const float*)d_in[9];
  const float* BT  = (const float*)d_in[10];
  float* ws  = (float*)d_ws;
  float* out = (float*)d_out;

  k_am  <<<N_SZ, 256, 0, stream>>>(AT, me, BT, ws);
  k_bw  <<<2, 256, 0, stream>>>(BT, Wm, ws);
  k_wmm <<<N_SZ, 256, 0, stream>>>(Wm, ws);
  k_ux  <<<T_LEN, 256, 0, stream>>>(x, ie, ws);
  k_xt  <<<T_LEN*4, 256, 0, stream>>>(x, ws);
  k_init<<<25, 256, 0, stream>>>(h0, m0, ws);
  k_scan<<<GS, NT, 0, stream>>>(Wh, Wi, he, BT, ws, out);
}

// Round 5
// 9326.038 us; speedup vs baseline: 3.4806x; 1.1377x over previous
//
#include <hip/hip_runtime.h>
#include <math.h>

#define T_LEN 2048
#define B_SZ  32
#define D_IN  128
#define U_SZ  512
#define N_SZ  256
#define GS    128
#define NT    512

// workspace offsets (in floats)
constexpr size_t OFF_AM  = 0;                                  // Am [256][256]
constexpr size_t OFF_WMM = OFF_AM  + (size_t)N_SZ*N_SZ;        // Wmm [256][512]
constexpr size_t OFF_BW  = OFF_WMM + (size_t)N_SZ*U_SZ;        // bw [512]
constexpr size_t OFF_UX  = OFF_BW  + U_SZ;                     // ux [2048][32]
constexpr size_t OFF_XT  = OFF_UX  + (size_t)T_LEN*B_SZ;       // xT [2048][128][32]
constexpr size_t OFF_S   = OFF_XT  + (size_t)T_LEN*D_IN*B_SZ;  // S [2][768][32]
constexpr size_t OFF_FLG = OFF_S   + (size_t)2*768*B_SZ;       // flags [128][16]

#define FMA4(A, S0, W0) \
  A.x = fmaf(S0, W0.x, A.x); A.y = fmaf(S0, W0.y, A.y); \
  A.z = fmaf(S0, W0.z, A.z); A.w = fmaf(S0, W0.w, A.w);

// one butterfly round over all 28 partial values (same bt, ks^mask/8)
#define REDR(m) \
  a0.x += __shfl_xor(a0.x,(m)); a0.y += __shfl_xor(a0.y,(m)); \
  a0.z += __shfl_xor(a0.z,(m)); a0.w += __shfl_xor(a0.w,(m)); \
  a1.x += __shfl_xor(a1.x,(m)); a1.y += __shfl_xor(a1.y,(m)); \
  a1.z += __shfl_xor(a1.z,(m)); a1.w += __shfl_xor(a1.w,(m)); \
  a2.x += __shfl_xor(a2.x,(m)); a2.y += __shfl_xor(a2.y,(m)); \
  a2.z += __shfl_xor(a2.z,(m)); a2.w += __shfl_xor(a2.w,(m)); \
  a3.x += __shfl_xor(a3.x,(m)); a3.y += __shfl_xor(a3.y,(m)); \
  a3.z += __shfl_xor(a3.z,(m)); a3.w += __shfl_xor(a3.w,(m)); \
  q0.x += __shfl_xor(q0.x,(m)); q0.y += __shfl_xor(q0.y,(m)); \
  q0.z += __shfl_xor(q0.z,(m)); q0.w += __shfl_xor(q0.w,(m)); \
  q1.x += __shfl_xor(q1.x,(m)); q1.y += __shfl_xor(q1.y,(m)); \
  q1.z += __shfl_xor(q1.z,(m)); q1.w += __shfl_xor(q1.w,(m)); \
  sa.x += __shfl_xor(sa.x,(m)); sa.y += __shfl_xor(sa.y,(m)); \
  sa.z += __shfl_xor(sa.z,(m)); sa.w += __shfl_xor(sa.w,(m));

// ---- fence-free cross-XCD primitives: sc1 (agent-scope) ops bypass the
// non-coherent per-XCD L2 and are served at the device coherence point ----
__device__ inline void st_agent_f1(float* p, float f) {
  union { float f; unsigned u; } c; c.f = f;
  __hip_atomic_store((unsigned*)p, c.u, __ATOMIC_RELAXED, __HIP_MEMORY_SCOPE_AGENT);
}
// 16B agent-scope load, issue-only (no wait) — caller must s_waitcnt vmcnt.
// sc1 = same cache-bypass bit __hip_atomic_load(AGENT) emits; per-element
// atomicity is irrelevant (single producer per float + flag handshake).
__device__ inline void ld_agent_f4_issue(float4* dst, const float* p) {
  asm volatile("global_load_dwordx4 %0, %1, off sc1"
               : "=v"(*dst) : "v"(p));
}

// Am[k][j] = AT[k][j] + I + me[k]*BT[j]   (folds m@me term of u into m-recurrence)
__global__ void k_am(const float* __restrict__ AT, const float* __restrict__ me,
                     const float* __restrict__ BT, float* __restrict__ ws) {
  int k = blockIdx.x, j = threadIdx.x;
  float v = AT[(size_t)k*N_SZ + j] + (k == j ? 1.0f : 0.0f) + me[k]*BT[j];
  ws[OFF_AM + (size_t)k*N_SZ + j] = v;
}

// bw[j] = sum_q BT[q]*Wm[q][j]
__global__ void k_bw(const float* __restrict__ BT, const float* __restrict__ Wm,
                     float* __restrict__ ws) {
  int j = blockIdx.x*256 + threadIdx.x;
  float acc = 0.f;
  for (int q = 0; q < N_SZ; ++q) acc += BT[q]*Wm[(size_t)q*U_SZ + j];
  ws[OFF_BW + j] = acc;
}

// Wmm = Am @ Wm   [256][512]
__global__ void k_wmm(const float* __restrict__ Wm, float* __restrict__ ws) {
  __shared__ float amr[N_SZ];
  int k = blockIdx.x, tid = threadIdx.x;
  amr[tid] = ws[OFF_AM + (size_t)k*N_SZ + tid];
  __syncthreads();
  float acc0 = 0.f, acc1 = 0.f;
  for (int q = 0; q < N_SZ; ++q) {
    float a = amr[q];
    acc0 += a * Wm[(size_t)q*U_SZ + tid];
    acc1 += a * Wm[(size_t)q*U_SZ + tid + 256];
  }
  ws[OFF_WMM + (size_t)k*U_SZ + tid]       = acc0;
  ws[OFF_WMM + (size_t)k*U_SZ + tid + 256] = acc1;
}

// ux[t][b] = x[b][t][:] . ie
__global__ void k_ux(const float* __restrict__ x, const float* __restrict__ ie,
                     float* __restrict__ ws) {
  __shared__ __align__(16) float iel[D_IN];
  __shared__ float red[B_SZ*9];
  int t = blockIdx.x, tid = threadIdx.x;
  if (tid < D_IN) iel[tid] = ie[tid];
  __syncthreads();
  int b = tid >> 3, p = tid & 7;
  const float4* xr = (const float4*)(x + ((size_t)b*T_LEN + t)*D_IN);
  const float4* wr = (const float4*)iel;
  float s = 0.f;
  for (int q = 0; q < 4; ++q) {
    int fi = p + q*8;
    float4 v = xr[fi];
    float4 w = wr[fi];
    s += v.x*w.x + v.y*w.y + v.z*w.z + v.w*w.w;
  }
  red[b*9 + p] = s;
  __syncthreads();
  if (tid < B_SZ) {
    float acc = 0.f;
    for (int p2 = 0; p2 < 8; ++p2) acc += red[tid*9 + p2];
    ws[OFF_UX + (size_t)t*B_SZ + tid] = acc;
  }
}

// xT[t][d][b] = x[b][t][d]
__global__ void k_xt(const float* __restrict__ x, float* __restrict__ ws) {
  __shared__ float tile[B_SZ*33];
  int bid = blockIdx.x;
  int t = bid >> 2, d0 = (bid & 3)*32;
  int tid = threadIdx.x;
  int lo = tid & 31, hi = tid >> 5;
  for (int p = 0; p < 4; ++p) {
    int b = hi + p*8;
    tile[b*33 + lo] = x[((size_t)b*T_LEN + t)*D_IN + d0 + lo];
  }
  __syncthreads();
  float* dst = ws + OFF_XT + ((size_t)t*D_IN + d0)*B_SZ;
  for (int p = 0; p < 4; ++p) {
    int d = hi + p*8;
    dst[(size_t)d*B_SZ + lo] = tile[lo*33 + d];
  }
}

// init: S[0] = [h0 | m0] in [k][b]; zero the barrier flags
__global__ void k_init(const float* __restrict__ h0, const float* __restrict__ mm0,
                       float* __restrict__ ws) {
  int bid = blockIdx.x, tid = threadIdx.x;
  if (bid < 24) {
    for (int i = 0; i < 4; ++i) {
      int e = bid*1024 + i*256 + tid;
      int k = e >> 5, b = e & 31;
      float v = (k < U_SZ) ? h0[(size_t)b*U_SZ + k] : mm0[(size_t)b*N_SZ + (k - U_SZ)];
      ws[OFF_S + e] = v;
    }
  } else {
    for (int idx = tid; idx < GS*16; idx += 256) ws[OFF_FLG + idx] = 0.0f;  // 0u bits
  }
}

// persistent scan: GS=128 blocks x NT=512 threads.
// Block g owns h-cols [g*4, g*4+4) and m-cols [g*2, g*2+2).
// This round: all 12 state loads per thread issued up-front as
// global_load_dwordx4 sc1 into registers, ONE s_waitcnt vmcnt(0), then pure
// register FMAs — pays the ~900cy IC latency once per step instead of per
// load-group (R3's VGPR_Count=56 showed the compiler serialized the atomic
// loads). Exchange protocol unchanged from the proven round-0 structure.
__global__ __launch_bounds__(NT, 2) void k_scan(
    const float* __restrict__ Wh, const float* __restrict__ Wi,
    const float* __restrict__ he, const float* __restrict__ btv,
    float* __restrict__ ws, float* __restrict__ out)
{
  const int g = blockIdx.x, tid = threadIdx.x;
  const int JH = g*4, JM = g*2;
  const int bt = tid & 7, ks = tid >> 3;   // ks in [0,64)
  const int b0 = bt*4;

  float* uxw = ws + OFF_UX;
  float* xT  = ws + OFF_XT;
  float* Sb  = ws + OFF_S;
  unsigned* flags = (unsigned*)(ws + OFF_FLG);

  __shared__ __align__(16) float Wl[896*4];   // [k][j]: k<512 Wh, <768 Wmm, <896 Wi
  __shared__ __align__(16) float Aml[N_SZ*2]; // [k][jm] m-columns of Am
  __shared__ float Hl[U_SZ];                  // hidden_encoders
  __shared__ __align__(16) float redh[64*20]; // [writer][j*4+b]
  __shared__ __align__(16) float redm[64*12]; // [writer][jm*4+b]
  __shared__ __align__(16) float reds[64*8];  // [writer][b]
  __shared__ float bwl[4], btl[2];

  for (int idx = tid; idx < 896*4; idx += NT) {
    int k = idx >> 2, jj = idx & 3;
    float v;
    if (k < 512)      v = Wh[(size_t)k*U_SZ + JH + jj];
    else if (k < 768) v = ws[OFF_WMM + (size_t)(k-512)*U_SZ + JH + jj];
    else              v = Wi[(size_t)(k-768)*U_SZ + JH + jj];
    Wl[idx] = v;
  }
  for (int idx = tid; idx < N_SZ*2; idx += NT) {
    int k = idx >> 1, jj = idx & 1;
    Aml[idx] = ws[OFF_AM + (size_t)k*N_SZ + JM + jj];
  }
  for (int idx = tid; idx < U_SZ; idx += NT) Hl[idx] = he[idx];
  if (tid < 4) bwl[tid] = ws[OFF_BW + JH + tid];
  if (tid < 2) btl[tid] = btv[JM + tid];
  __syncthreads();

  const float4* Wl4  = (const float4*)Wl;
  const float2* Aml2 = (const float2*)Aml;

  // accumulators: a{0..3} = h-col JH+{0..3} over this thread's 4 batches;
  // q{0,1} = m-col JM+{0,1}; sa = h.he partial.
  float4 a0={0,0,0,0}, a1={0,0,0,0}, a2={0,0,0,0}, a3={0,0,0,0};
  // seg3 for t=0 (x_0 @ Wi), local data only
  {
    const float* xrow = xT;
    #pragma unroll
    for (int i = 12; i < 14; ++i) {
      int kk = i*64 + ks;
      float4 sv = *(const float4*)(xrow + (size_t)(kk - 768)*B_SZ + b0);
      float4 wv = Wl4[kk];
      FMA4(a0, wv.x, sv) FMA4(a1, wv.y, sv) FMA4(a2, wv.z, sv) FMA4(a3, wv.w, sv)
    }
  }

  for (int t = 0; t < T_LEN; ++t) {
    const float* S  = Sb + (size_t)(t & 1)*(768*B_SZ);
    float*       Sn = Sb + (size_t)((t+1) & 1)*(768*B_SZ);

    float uxv = uxw[(size_t)t*B_SZ + (tid & 31)];

    float4 q0={0,0,0,0}, q1={0,0,0,0};
    float4 sa={0,0,0,0};

    // ---- stage ALL 12 state vectors (16B sc1 loads), one wait, then FMA ----
    float4 sv0, sv1, sv2, sv3, sv4, sv5, sv6, sv7, sv8, sv9, sv10, sv11;
    ld_agent_f4_issue(&sv0,  S + (size_t)( 0*64 + ks)*B_SZ + b0);
    ld_agent_f4_issue(&sv1,  S + (size_t)( 1*64 + ks)*B_SZ + b0);
    ld_agent_f4_issue(&sv2,  S + (size_t)( 2*64 + ks)*B_SZ + b0);
    ld_agent_f4_issue(&sv3,  S + (size_t)( 3*64 + ks)*B_SZ + b0);
    ld_agent_f4_issue(&sv4,  S + (size_t)( 4*64 + ks)*B_SZ + b0);
    ld_agent_f4_issue(&sv5,  S + (size_t)( 5*64 + ks)*B_SZ + b0);
    ld_agent_f4_issue(&sv6,  S + (size_t)( 6*64 + ks)*B_SZ + b0);
    ld_agent_f4_issue(&sv7,  S + (size_t)( 7*64 + ks)*B_SZ + b0);
    ld_agent_f4_issue(&sv8,  S + (size_t)( 8*64 + ks)*B_SZ + b0);
    ld_agent_f4_issue(&sv9,  S + (size_t)( 9*64 + ks)*B_SZ + b0);
    ld_agent_f4_issue(&sv10, S + (size_t)(10*64 + ks)*B_SZ + b0);
    ld_agent_f4_issue(&sv11, S + (size_t)(11*64 + ks)*B_SZ + b0);
    asm volatile("s_waitcnt vmcnt(0)" ::: "memory");
    __builtin_amdgcn_sched_barrier(0);   // rule #18: keep FMAs below the wait

    // seg1: k in [0,512): h x Wh (+ local s-partial h.he)
    #define SEG1(I, SV) { \
      int kk = (I)*64 + ks; \
      float4 wv = Wl4[kk]; \
      float hv = Hl[kk]; \
      FMA4(a0, wv.x, SV) FMA4(a1, wv.y, SV) FMA4(a2, wv.z, SV) FMA4(a3, wv.w, SV) \
      FMA4(sa, hv, SV) }
    SEG1(0, sv0) SEG1(1, sv1) SEG1(2, sv2) SEG1(3, sv3)
    SEG1(4, sv4) SEG1(5, sv5) SEG1(6, sv6) SEG1(7, sv7)
    #undef SEG1
    // seg2: k in [512,768): m x Wmm  +  m x Am
    #define SEG2(I, SV) { \
      int kk = (I)*64 + ks; \
      float4 wv = Wl4[kk]; \
      FMA4(a0, wv.x, SV) FMA4(a1, wv.y, SV) FMA4(a2, wv.z, SV) FMA4(a3, wv.w, SV) \
      float2 av = Aml2[kk - 512]; \
      FMA4(q0, av.x, SV) FMA4(q1, av.y, SV) }
    SEG2(8, sv8) SEG2(9, sv9) SEG2(10, sv10) SEG2(11, sv11)
    #undef SEG2

    // in-wave ks-reduction: 3 butterfly rounds (ks^1, ks^2, ks^4 in-wave)
    REDR(8) REDR(16) REDR(32)

    // LDS partials: one writer per (bt, wave) = 64 writers
    if ((tid & 56) == 0) {
      const int wi = bt + 8*(tid >> 6);
      float4* rp = (float4*)(redh + wi*20);
      rp[0] = a0; rp[1] = a1; rp[2] = a2; rp[3] = a3;
      float4* rm = (float4*)(redm + wi*12);
      rm[0] = q0; rm[1] = q1;
      *(float4*)(reds + wi*8) = sa;
    }
    __syncthreads();   // (A)

    // epilogue: tid<128 -> h-cols (be,je); tid in [128,192) -> m-cols (be,jm)
    float val = 0.f;
    if (tid < 192) {
      const int be2 = tid & 31, btb = be2 >> 2, xx = be2 & 3;
      float ssb = uxv;
      #pragma unroll
      for (int wv = 0; wv < 8; ++wv) ssb += reds[(btb + 8*wv)*8 + xx];
      if (tid < 128) {
        const int je = tid >> 5;
        float sum = 0.f;
        #pragma unroll
        for (int wv = 0; wv < 8; ++wv)
          sum += redh[(btb + 8*wv)*20 + je*4 + xx];
        val = tanhf(sum + ssb*bwl[je]);
        st_agent_f1(Sn + (size_t)(JH + je)*B_SZ + be2, val);
      } else {
        const int jm = (tid - 128) >> 5;
        float sum = 0.f;
        #pragma unroll
        for (int wv = 0; wv < 8; ++wv)
          sum += redm[(btb + 8*wv)*12 + jm*4 + xx];
        sum += ssb*btl[jm];
        st_agent_f1(Sn + (size_t)(512 + JM + jm)*B_SZ + be2, sum);
      }
    }
    __syncthreads();   // (B) — implicit vmcnt(0): all Sn sc1 stores are at IC

    // arrival flag ASAP, then off-critical-path work in the barrier shadow
    if (t + 1 < T_LEN && tid == 0)
      __hip_atomic_store(flags + (size_t)g*16, (unsigned)(t + 1),
                         __ATOMIC_RELAXED, __HIP_MEMORY_SCOPE_AGENT);
    if (tid < 128)
      out[((size_t)(tid & 31)*T_LEN + t)*U_SZ + JH + (tid >> 5)] = val;

    a0.x=a0.y=a0.z=a0.w=0.f; a1=a0; a2=a0; a3=a0;
    if (t + 1 < T_LEN) {
      const float* xrow = xT + (size_t)(t+1)*D_IN*B_SZ;
      #pragma unroll
      for (int i = 12; i < 14; ++i) {
        int kk = i*64 + ks;
        float4 sv = *(const float4*)(xrow + (size_t)(kk - 768)*B_SZ + b0);
        float4 wv = Wl4[kk];
        FMA4(a0, wv.x, sv) FMA4(a1, wv.y, sv) FMA4(a2, wv.z, sv) FMA4(a3, wv.w, sv)
      }
      if (tid < GS) {
        const unsigned* fp = flags + (size_t)tid*16;
        while (__hip_atomic_load(fp, __ATOMIC_RELAXED, __HIP_MEMORY_SCOPE_AGENT)
               < (unsigned)(t + 1)) { }
      }
    }
    __syncthreads();   // (C)
  }
}

extern "C" void kernel_launch(void* const* d_in, const int* in_sizes, int n_in,
                              void* d_out, int out_size, void* d_ws, size_t ws_size,
                              hipStream_t stream) {
  const float* x   = (const float*)d_in[0];
  const float* h0  = (const float*)d_in[1];
  const float* m0  = (const float*)d_in[2];
  const float* ie  = (const float*)d_in[3];
  const float* he  = (const float*)d_in[4];
  const float* me  = (const float*)d_in[5];
  const float* Wi  = (const float*)d_in[6];
  const float* Wh  = (const float*)d_in[7];
  const float* Wm  = (const float*)d_in[8];
  const float* AT  = (const float*)d_in[9];
  const float* BT  = (const float*)d_in[10];
  float* ws  = (float*)d_ws;
  float* out = (float*)d_out;

  k_am  <<<N_SZ, 256, 0, stream>>>(AT, me, BT, ws);
  k_bw  <<<2, 256, 0, stream>>>(BT, Wm, ws);
  k_wmm <<<N_SZ, 256, 0, stream>>>(Wm, ws);
  k_ux  <<<T_LEN, 256, 0, stream>>>(x, ie, ws);
  k_xt  <<<T_LEN*4, 256, 0, stream>>>(x, ws);
  k_init<<<25, 256, 0, stream>>>(h0, m0, ws);
  k_scan<<<GS, NT, 0, stream>>>(Wh, Wi, he, BT, ws, out);
}